// Round 2
// baseline (358.097 us; speedup 1.0000x reference)
//
#include <hip/hip_runtime.h>

// Problem constants (fixed by the reference).
#define NGRID 262144      // N = 64^3 = 2^18
#define NNZ_C 1835008     // 7 * N
#define BSZ   32

// ---------------------------------------------------------------------------
// Block reduction for 256-thread blocks (4 waves of 64).
// Returns full sum in thread 0 only.
// ---------------------------------------------------------------------------
__device__ __forceinline__ float block_reduce_sum_256(float v) {
    __shared__ float red[4];
    #pragma unroll
    for (int o = 32; o > 0; o >>= 1) v += __shfl_down(v, o);
    const int wave = threadIdx.x >> 6;
    const int lane = threadIdx.x & 63;
    if (lane == 0) red[wave] = v;
    __syncthreads();
    float s = 0.f;
    if (threadIdx.x == 0) {
        #pragma unroll
        for (int i = 0; i < 4; ++i) s += red[i];
    }
    return s;
}

// ---------------------------------------------------------------------------
// K1: transpose y_pred (32,N) -> yp_t (N,32); also zero yat_t (N,32).
// LDS tile 64n x 32b with +1 pad: both phases conflict-free (2-way max).
// grid = N/64 blocks x 256 threads.
// ---------------------------------------------------------------------------
__global__ void k_transpose_zero(const float* __restrict__ yp,
                                 float* __restrict__ yp_t,
                                 float* __restrict__ yat_t) {
    __shared__ float tile[64 * 33];
    const int tid = threadIdx.x;
    const size_t n0 = (size_t)blockIdx.x * 64;
    const int lane_n = tid & 63;    // wave reads 64 consecutive n of one row
    const int bq = tid >> 6;        // wave id 0..3
    #pragma unroll
    for (int r = 0; r < 8; ++r) {
        const int b = bq * 8 + r;
        tile[lane_n * 33 + b] = yp[(size_t)b * NGRID + n0 + lane_n];
    }
    __syncthreads();
    #pragma unroll
    for (int w = 0; w < 8; ++w) {
        const int f = w * 256 + tid;            // 0..2047 flat (n-major, b-minor)
        yp_t[n0 * 32 + f] = tile[(f >> 5) * 33 + (f & 31)];
        yat_t[n0 * 32 + f] = 0.f;               // zero-init scatter target
    }
}

// ---------------------------------------------------------------------------
// K2: COO scatter. thread -> (edge e = tid>>5, batch b = tid&31).
// Gather yp_t[c*32+b]: 32 lanes hit one contiguous 128B line per edge.
// atomicAdd into yat_t[r*32+b]: same contiguity.
// grid = NNZ*32/256 blocks (exact).
// ---------------------------------------------------------------------------
__global__ void k_scatter(const float* __restrict__ vals,
                          const int* __restrict__ rows,
                          const int* __restrict__ cols,
                          const float* __restrict__ yp_t,
                          float* __restrict__ yat_t) {
    const size_t tid = (size_t)blockIdx.x * blockDim.x + threadIdx.x;
    const int b = (int)(tid & 31);
    const size_t e = tid >> 5;
    const float v = vals[e];
    const int r = rows[e];
    const int c = cols[e];
    const float x = yp_t[(size_t)c * 32 + b];
    atomicAdd(&yat_t[(size_t)r * 32 + b], v * x);
}

// ---------------------------------------------------------------------------
// K3: YhatY partials — batched dot <y_true[b], y_pred[b]>, (B,N) layout.
// grid = (64, 32); p1[b*64 + blockIdx.x].
// ---------------------------------------------------------------------------
__global__ void k_dot_yty(const float* __restrict__ yt,
                          const float* __restrict__ yp,
                          float* __restrict__ p1) {
    const int b = blockIdx.y;
    const float4* yt4 = (const float4*)(yt + (size_t)b * NGRID);
    const float4* yp4 = (const float4*)(yp + (size_t)b * NGRID);
    float acc = 0.f;
    for (int i = blockIdx.x * 256 + threadIdx.x; i < NGRID / 4; i += 64 * 256) {
        const float4 a = yt4[i];
        const float4 c = yp4[i];
        acc = fmaf(a.x, c.x, acc);
        acc = fmaf(a.y, c.y, acc);
        acc = fmaf(a.z, c.z, acc);
        acc = fmaf(a.w, c.w, acc);
    }
    const float s = block_reduce_sum_256(acc);
    if (threadIdx.x == 0) p1[b * 64 + blockIdx.x] = s;
}

// ---------------------------------------------------------------------------
// K4: YhatYhatAt partials — flat dot over transposed arrays.
// float4 at index i covers b = (4i)&31 .. +3; stride keeps b residues fixed
// per thread. LDS position p=4*tid+j satisfies p&31 == b.
// grid = 256 blocks; p2[blockIdx.x*32 + b].
// ---------------------------------------------------------------------------
__global__ void k_dot_yyat(const float* __restrict__ yp_t,
                           const float* __restrict__ yat_t,
                           float* __restrict__ p2) {
    __shared__ float lds[1024];
    float acc[4] = {0.f, 0.f, 0.f, 0.f};
    const float4* a4 = (const float4*)yp_t;
    const float4* b4 = (const float4*)yat_t;
    for (int i = blockIdx.x * 256 + threadIdx.x; i < (NGRID * 32) / 4; i += 256 * 256) {
        const float4 a = a4[i];
        const float4 b = b4[i];
        acc[0] = fmaf(a.x, b.x, acc[0]);
        acc[1] = fmaf(a.y, b.y, acc[1]);
        acc[2] = fmaf(a.z, b.z, acc[2]);
        acc[3] = fmaf(a.w, b.w, acc[3]);
    }
    #pragma unroll
    for (int j = 0; j < 4; ++j) lds[threadIdx.x * 4 + j] = acc[j];
    __syncthreads();
    if (threadIdx.x < 32) {
        float s = 0.f;
        for (int k = 0; k < 32; ++k) s += lds[threadIdx.x + 32 * k];
        p2[blockIdx.x * 32 + threadIdx.x] = s;
    }
}

// ---------------------------------------------------------------------------
// K5: alpha[b] = YhatY[b] / YhatYhatAt[b]. 1 block x 32 threads.
// ---------------------------------------------------------------------------
__global__ void k_alpha(const float* __restrict__ p1,
                        const float* __restrict__ p2,
                        float* __restrict__ alpha) {
    const int b = threadIdx.x;
    float s1 = 0.f, s2 = 0.f;
    for (int j = 0; j < 64; ++j) s1 += p1[b * 64 + j];
    for (int k = 0; k < 256; ++k) s2 += p2[k * 32 + b];
    alpha[b] = s1 / s2;
}

// ---------------------------------------------------------------------------
// K6: loss partials. Per block: LDS tile of yat_t (256n x 32b, pad 33),
// loaded flat-coalesced; compute phase reads y_true 256B/wave coalesced and
// tile[nl*33+b] conflict-free ((nl+b)%32 distinct across lanes).
// Each thread: b = wave*8 + j (j<8) covers all 32 batches; nl = c*64+lane
// (c<4) covers all 256 n -> 8192 elements per block, each exactly once.
// grid = N/256 blocks; p3[blockIdx.x].
// ---------------------------------------------------------------------------
__global__ void k_loss(const float* __restrict__ yt,
                       const float* __restrict__ yat_t,
                       const float* __restrict__ alpha,
                       float* __restrict__ p3) {
    __shared__ float tile[256 * 33];
    __shared__ float a_sh[32];
    const int tid = threadIdx.x;
    if (tid < 32) a_sh[tid] = alpha[tid];
    const size_t n0 = (size_t)blockIdx.x * 256;
    #pragma unroll
    for (int w = 0; w < 32; ++w) {
        const int f = w * 256 + tid;            // 0..8191
        tile[(f >> 5) * 33 + (f & 31)] = yat_t[n0 * 32 + f];
    }
    __syncthreads();
    const int wave = tid >> 6;
    const int lane = tid & 63;
    float acc = 0.f;
    #pragma unroll
    for (int j = 0; j < 8; ++j) {
        const int b = wave * 8 + j;             // 0..31 — full batch coverage
        const float a = a_sh[b];
        const float* ytr = yt + (size_t)b * NGRID + n0;
        #pragma unroll
        for (int c = 0; c < 4; ++c) {
            const int nl = c * 64 + lane;
            const float t = ytr[nl];
            const float yv = tile[nl * 33 + b];
            const float r = fmaf(-a, yv, t);
            acc = fmaf(r, r, acc);
        }
    }
    const float s = block_reduce_sum_256(acc);
    if (tid == 0) p3[blockIdx.x] = s;
}

// ---------------------------------------------------------------------------
// K7: final reduce of 1024 partials; mean over batch = sum / 32.
// ---------------------------------------------------------------------------
__global__ void k_final(const float* __restrict__ p3, float* __restrict__ out) {
    float acc = 0.f;
    for (int i = threadIdx.x; i < 1024; i += 256) acc += p3[i];
    const float s = block_reduce_sum_256(acc);
    if (threadIdx.x == 0) out[0] = s * (1.0f / 32.0f);
}

extern "C" void kernel_launch(void* const* d_in, const int* in_sizes, int n_in,
                              void* d_out, int out_size, void* d_ws, size_t ws_size,
                              hipStream_t stream) {
    const float* yp = (const float*)d_in[0];   // y_pred (32, N)
    const float* yt = (const float*)d_in[1];   // y_true (32, N)
    const float* Av = (const float*)d_in[2];   // A_vals (NNZ)
    const int*   Ar = (const int*)d_in[3];     // A_rows (NNZ)
    const int*   Ac = (const int*)d_in[4];     // A_cols (NNZ)
    float* out = (float*)d_out;

    // Workspace layout (floats). Total ~16.79M floats = 67.2 MB.
    float* ws    = (float*)d_ws;
    float* yp_t  = ws;                              // N*32
    float* yat_t = yp_t + (size_t)NGRID * 32;       // N*32
    float* p1    = yat_t + (size_t)NGRID * 32;      // 32*64
    float* p2    = p1 + 32 * 64;                    // 256*32
    float* alpha = p2 + 256 * 32;                   // 32
    float* p3    = alpha + 32;                      // 1024

    k_transpose_zero<<<NGRID / 64, 256, 0, stream>>>(yp, yp_t, yat_t);
    k_scatter<<<(NNZ_C * 32) / 256, 256, 0, stream>>>(Av, Ar, Ac, yp_t, yat_t);
    k_dot_yty<<<dim3(64, 32), 256, 0, stream>>>(yt, yp, p1);
    k_dot_yyat<<<256, 256, 0, stream>>>(yp_t, yat_t, p2);
    k_alpha<<<1, 32, 0, stream>>>(p1, p2, alpha);
    k_loss<<<NGRID / 256, 256, 0, stream>>>(yt, yat_t, alpha, p3);
    k_final<<<1, 256, 0, stream>>>(p3, out);
}